// Round 3
// baseline (738.131 us; speedup 1.0000x reference)
//
#include <hip/hip_runtime.h>
#include <math.h>

#define NTOK 768
#define CS   384
#define CZ   128
#define NH   12
#define PQn  4
#define PVn  8
#define INF_ 100000.0f
#define EPS_ 1e-8f

// ---------------------------------------------------------------------------
// K1: projections from s + rigid transform of points.
// Outputs: Q[n][h*16+c], KT[h*16+c][n], VT[h*16+c][n],
//          QP[n][(h*4+p)*3+x], KPT[(h*4+p)*3+x][n], VPT[(h*8+p)*3+x][n]
// Work items: 192 (q) + 384 (k,v) + 48 (q_pts) + 144 (kv_pts) = 768 total.
// ---------------------------------------------------------------------------
__global__ __launch_bounds__(256) void k1_proj(
    const float* __restrict__ s, const float* __restrict__ rot, const float* __restrict__ trans,
    const float* __restrict__ wq, const float* __restrict__ bq,
    const float* __restrict__ wkv, const float* __restrict__ bkv,
    const float* __restrict__ wqp, const float* __restrict__ bqp,
    const float* __restrict__ wkvp, const float* __restrict__ bkvp,
    float* __restrict__ Q, float* __restrict__ KT, float* __restrict__ VT,
    float* __restrict__ QP, float* __restrict__ KPT, float* __restrict__ VPT)
{
    __shared__ float sL[CS];
    const int n = blockIdx.x;
    const int tid = threadIdx.x;
    for (int k = tid; k < CS; k += 256) sL[k] = s[n * CS + k];
    __syncthreads();

    float R[9], T[3];
    #pragma unroll
    for (int x = 0; x < 9; x++) R[x] = rot[n * 9 + x];
    #pragma unroll
    for (int x = 0; x < 3; x++) T[x] = trans[n * 3 + x];

    for (int item = tid; item < 768; item += 256) {     // FIX: was 1152 (OOB strays corrupted VPT)
        if (item < 192) {                       // q
            const int col = item;
            float acc = bq[col];
            for (int k = 0; k < CS; k++) acc += sL[k] * wq[k * 192 + col];
            Q[n * 192 + col] = acc;
        } else if (item < 576) {                // k, v  (kv cols: h*32 + [0..15]=k, [16..31]=v)
            const int r = item - 192;
            const bool isV = (r >= 192);
            const int idx = isV ? r - 192 : r;  // h*16+c
            const int h = idx >> 4, c = idx & 15;
            const int col = h * 32 + (isV ? 16 : 0) + c;
            float acc = bkv[col];
            for (int k = 0; k < CS; k++) acc += sL[k] * wkv[k * 384 + col];
            if (isV) VT[idx * NTOK + n] = acc;
            else     KT[idx * NTOK + n] = acc;
        } else if (item < 624) {                // q points: pidx in 0..47 (pidx = h*4+p)
            const int pidx = item - 576;
            float raw[3];
            #pragma unroll
            for (int x = 0; x < 3; x++) {
                const int col = x * 48 + pidx;
                float acc = bqp[col];
                for (int k = 0; k < CS; k++) acc += sL[k] * wqp[k * 144 + col];
                raw[x] = acc;
            }
            #pragma unroll
            for (int x = 0; x < 3; x++) {
                const float v = R[x*3+0]*raw[0] + R[x*3+1]*raw[1] + R[x*3+2]*raw[2] + T[x];
                QP[n * 144 + pidx * 3 + x] = v;
            }
        } else {                                // kv points: pidx in 0..143 (pidx = h*12+pp)
            const int pidx = item - 624;
            float raw[3];
            #pragma unroll
            for (int x = 0; x < 3; x++) {
                const int col = x * 144 + pidx;
                float acc = bkvp[col];
                for (int k = 0; k < CS; k++) acc += sL[k] * wkvp[k * 432 + col];
                raw[x] = acc;
            }
            const int h = pidx / 12, pp = pidx % 12;
            #pragma unroll
            for (int x = 0; x < 3; x++) {
                const float v = R[x*3+0]*raw[0] + R[x*3+1]*raw[1] + R[x*3+2]*raw[2] + T[x];
                if (pp < PQn) KPT[((h * PQn + pp) * 3 + x) * NTOK + n] = v;
                else          VPT[((h * PVn + (pp - PQn)) * 3 + x) * NTOK + n] = v;
            }
        }
    }
}

// ---------------------------------------------------------------------------
// K3 (fused): per row i — z-row projection (bias + pair_z) + logits + softmax
// + all weighted sums. 768 threads: one j per thread in phases 1-2.
// LDS: LB 36864 + PZ 98304 + wzL 22528 + small ≈ 155.5 KB (≤160 KB).
// ---------------------------------------------------------------------------
__global__ __launch_bounds__(768) void k3_fused(
    const float* __restrict__ z,
    const float* __restrict__ wb, const float* __restrict__ bb,
    const float* __restrict__ wdz, const float* __restrict__ bdz,
    const float* __restrict__ KT, const float* __restrict__ VT,
    const float* __restrict__ KPT, const float* __restrict__ VPT,
    const float* __restrict__ Q, const float* __restrict__ QP,
    const float* __restrict__ mask, const float* __restrict__ head_weights,
    float* __restrict__ O, float* __restrict__ OPT, float* __restrict__ OPAIR)
{
    __shared__ float LB[NH][NTOK];      // bias -> logits -> probs (in place)
    __shared__ float PZ[32][NTOK];      // pair_z for this row
    __shared__ float wzL[CZ * 44];      // [k][44]: o<12 -> wb, else wdz
    __shared__ float qrow[192], qprow[144], hwL[NH], biasL[44];

    const int i = blockIdx.x, tid = threadIdx.x;

    // ---- phase 0: stage weights + q row
    for (int idx = tid; idx < CZ * 44; idx += 768) {
        const int k = idx / 44, o = idx % 44;
        wzL[idx] = (o < 12) ? wb[k * 12 + o] : wdz[k * 32 + (o - 12)];
    }
    if (tid < 192) qrow[tid] = Q[i * 192 + tid];
    else if (tid >= 256 && tid < 400) qprow[tid - 256] = QP[i * 144 + (tid - 256)];
    else if (tid >= 448 && tid < 460)
        hwL[tid - 448] = logf(1.0f + expf(head_weights[tid - 448])) * 0.13608276348795434f; // sqrt(1/54)
    else if (tid >= 512 && tid < 556)
        biasL[tid - 512] = (tid - 512 < 12) ? bb[tid - 512] : bdz[tid - 512 - 12];
    __syncthreads();

    // ---- phase 1: z-row projection, one j per thread
    const int j = tid;
    {
        const float4* zrow = (const float4*)(z + ((size_t)i * NTOK + j) * CZ);
        float acc[44];
        #pragma unroll
        for (int o = 0; o < 44; o++) acc[o] = biasL[o];
        for (int k4 = 0; k4 < CZ / 4; k4++) {
            const float4 zv = zrow[k4];
            const float* w0 = &wzL[(k4 * 4) * 44];
            #pragma unroll
            for (int o = 0; o < 44; o++)
                acc[o] += zv.x * w0[o] + zv.y * w0[o + 44] + zv.z * w0[o + 88] + zv.w * w0[o + 132];
        }
        #pragma unroll
        for (int h = 0; h < NH; h++) LB[h][j] = acc[h];
        #pragma unroll
        for (int c = 0; c < 32; c++) PZ[c][j] = acc[12 + c];
    }
    __syncthreads();

    // ---- phase 2: logits
    const float qk_scale = 0.14433756729740643f;   // sqrt(1/48)
    const float b_scale  = 0.5773502691896258f;    // sqrt(1/3)
    const float mterm = INF_ * (mask[i] * mask[j] - 1.0f);
    #pragma unroll 1
    for (int h = 0; h < NH; h++) {
        float qk = 0.0f;
        #pragma unroll
        for (int c = 0; c < 16; c++)
            qk += qrow[h * 16 + c] * KT[(h * 16 + c) * NTOK + j];
        float pt = 0.0f;
        #pragma unroll
        for (int d = 0; d < 12; d++) {
            const float dv = qprow[h * 12 + d] - KPT[(h * 12 + d) * NTOK + j];
            pt += dv * dv;
        }
        LB[h][j] = qk * qk_scale + b_scale * LB[h][j] - 0.5f * hwL[h] * pt + mterm;
    }
    __syncthreads();

    // ---- phase 3: softmax, wave w handles head w (12 waves exactly)
    {
        const int h = tid >> 6, lane = tid & 63;
        float m = -3.0e38f;
        for (int jj = lane; jj < NTOK; jj += 64) m = fmaxf(m, LB[h][jj]);
        #pragma unroll
        for (int off = 32; off >= 1; off >>= 1) m = fmaxf(m, __shfl_xor(m, off));
        float ssum = 0.0f;
        for (int jj = lane; jj < NTOK; jj += 64) {
            const float e = __expf(LB[h][jj] - m);
            LB[h][jj] = e;
            ssum += e;
        }
        #pragma unroll
        for (int off = 32; off >= 1; off >>= 1) ssum += __shfl_xor(ssum, off);
        const float inv = 1.0f / ssum;
        for (int jj = lane; jj < NTOK; jj += 64) LB[h][jj] *= inv;
    }
    __syncthreads();

    // ---- phase 4: weighted sums: o(16) + o_pt(24) + o_pair(32) per head = 864
    for (int oidx = tid; oidx < 864; oidx += 768) {
        const int h = oidx / 72, r = oidx % 72;
        const float4* a4 = (const float4*)&LB[h][0];
        const float4* s4;
        if (r < 16)       s4 = (const float4*)&VT[(h * 16 + r) * NTOK];
        else if (r < 40)  s4 = (const float4*)&VPT[(h * 24 + (r - 16)) * NTOK];
        else              s4 = (const float4*)&PZ[r - 40][0];
        float acc = 0.0f;
        for (int j4 = 0; j4 < NTOK / 4; j4++) {
            const float4 a = a4[j4], v = s4[j4];
            acc += a.x * v.x + a.y * v.y + a.z * v.z + a.w * v.w;
        }
        if (r < 16)      O[i * 192 + h * 16 + r] = acc;
        else if (r < 40) OPT[i * 288 + h * 24 + (r - 16)] = acc;
        else             OPAIR[i * 384 + h * 32 + (r - 40)] = acc;
    }
}

// ---------------------------------------------------------------------------
// K4: inverse rotation + norms + concat + final linear (4 tokens / block)
// ---------------------------------------------------------------------------
#define K4T 4
__global__ __launch_bounds__(256) void k4_out(
    const float* __restrict__ O, const float* __restrict__ OPT, const float* __restrict__ OPAIR,
    const float* __restrict__ rot, const float* __restrict__ trans,
    const float* __restrict__ wout, const float* __restrict__ bout,
    float* __restrict__ out)
{
    __shared__ float f[K4T][960];
    const int n0 = blockIdx.x * K4T, tid = threadIdx.x;

    for (int idx = tid; idx < K4T * 192; idx += 256) {
        const int t = idx / 192, k = idx % 192;
        f[t][k] = O[(n0 + t) * 192 + k];
    }
    for (int idx = tid; idx < K4T * 384; idx += 256) {
        const int t = idx / 384, k = idx % 384;
        f[t][576 + k] = OPAIR[(n0 + t) * 384 + k];
    }
    for (int idx = tid; idx < K4T * 96; idx += 256) {
        const int t = idx / 96, hp = idx % 96;
        const int n = n0 + t;
        const float vx = OPT[n * 288 + hp * 3 + 0] - trans[n * 3 + 0];
        const float vy = OPT[n * 288 + hp * 3 + 1] - trans[n * 3 + 1];
        const float vz = OPT[n * 288 + hp * 3 + 2] - trans[n * 3 + 2];
        // out_y = sum_x rot[x][y] * v[x]   (R^T)
        const float o0 = rot[n*9+0]*vx + rot[n*9+3]*vy + rot[n*9+6]*vz;
        const float o1 = rot[n*9+1]*vx + rot[n*9+4]*vy + rot[n*9+7]*vz;
        const float o2 = rot[n*9+2]*vx + rot[n*9+5]*vy + rot[n*9+8]*vz;
        f[t][192 + hp] = o0;
        f[t][288 + hp] = o1;
        f[t][384 + hp] = o2;
        f[t][480 + hp] = sqrtf(o0*o0 + o1*o1 + o2*o2 + EPS_);
    }
    __syncthreads();

    for (int o = tid; o < 384; o += 256) {
        float acc[K4T];
        #pragma unroll
        for (int t = 0; t < K4T; t++) acc[t] = bout[o];
        for (int k = 0; k < 960; k++) {
            const float wv = wout[k * 384 + o];
            #pragma unroll
            for (int t = 0; t < K4T; t++) acc[t] += f[t][k] * wv;
        }
        #pragma unroll
        for (int t = 0; t < K4T; t++) out[(n0 + t) * 384 + o] = acc[t];
    }
}

// ---------------------------------------------------------------------------
extern "C" void kernel_launch(void* const* d_in, const int* in_sizes, int n_in,
                              void* d_out, int out_size, void* d_ws, size_t ws_size,
                              hipStream_t stream) {
    (void)in_sizes; (void)n_in; (void)out_size; (void)ws_size;
    const float* s     = (const float*)d_in[0];
    const float* z     = (const float*)d_in[1];
    const float* rot   = (const float*)d_in[2];
    const float* trans = (const float*)d_in[3];
    const float* mask  = (const float*)d_in[4];
    const float* wq    = (const float*)d_in[5];
    const float* bq    = (const float*)d_in[6];
    const float* wkv   = (const float*)d_in[7];
    const float* bkv   = (const float*)d_in[8];
    const float* wqp   = (const float*)d_in[9];
    const float* bqp   = (const float*)d_in[10];
    const float* wkvp  = (const float*)d_in[11];
    const float* bkvp  = (const float*)d_in[12];
    const float* wb    = (const float*)d_in[13];
    const float* bb    = (const float*)d_in[14];
    const float* wdz   = (const float*)d_in[15];
    const float* bdz   = (const float*)d_in[16];
    const float* hwts  = (const float*)d_in[17];
    const float* wout  = (const float*)d_in[18];
    const float* bout  = (const float*)d_in[19];
    float* out = (float*)d_out;

    float* ws = (float*)d_ws;
    float* Q     = ws;                       // 147456
    float* KT    = Q     + 147456;           // 147456
    float* VT    = KT    + 147456;           // 147456
    float* QP    = VT    + 147456;           // 110592
    float* KPT   = QP    + 110592;           // 110592
    float* VPT   = KPT   + 110592;           // 221184
    float* O     = VPT   + 221184;           // 147456
    float* OPT   = O     + 147456;           // 221184
    float* OPAIR = OPT   + 221184;           // 294912
    // total ws: 1,548,288 floats = 6.19 MB

    hipLaunchKernelGGL(k1_proj, dim3(NTOK), dim3(256), 0, stream,
                       s, rot, trans, wq, bq, wkv, bkv, wqp, bqp, wkvp, bkvp,
                       Q, KT, VT, QP, KPT, VPT);
    hipLaunchKernelGGL(k3_fused, dim3(NTOK), dim3(768), 0, stream,
                       z, wb, bb, wdz, bdz,
                       KT, VT, KPT, VPT, Q, QP, mask, hwts,
                       O, OPT, OPAIR);
    hipLaunchKernelGGL(k4_out, dim3(NTOK / K4T), dim3(256), 0, stream,
                       O, OPT, OPAIR, rot, trans, wout, bout, out);
}